// Round 8
// baseline (346.168 us; speedup 1.0000x reference)
//
#include <hip/hip_runtime.h>
#include <hip/hip_bf16.h>
#include <stdint.h>

typedef float v4f __attribute__((ext_vector_type(4)));
typedef short v8s __attribute__((ext_vector_type(8)));

#define NB 40

__device__ __forceinline__ unsigned short f2b(float f) {
  __hip_bfloat16 h = __float2bfloat16(f);
  unsigned short u;
  __builtin_memcpy(&u, &h, 2);
  return u;
}
__device__ __forceinline__ unsigned pk2(float lo, float hi) {
  __hip_bfloat162 h = __float22bfloat162_rn(make_float2(lo, hi));
  unsigned u;
  __builtin_memcpy(&u, &h, 4);
  return u;
}
__device__ __forceinline__ float b2f16(unsigned short h) {
  return __uint_as_float(((unsigned)h) << 16);
}
__device__ __forceinline__ float blo(unsigned u) { return __uint_as_float(u << 16); }
__device__ __forceinline__ float bhi(unsigned u) { return __uint_as_float(u & 0xFFFF0000u); }

// ws layout (bytes):
//  A1pk   @ 0        : 12288     (2t x 3nt x 2ks A^T A-frags, zero n>=40 / m>=40)
//  W2pk   @ 12288    : 32768     (2t x 4ks x 4dt B-frags of gnn_w)
//  Gpk    @ 45056    : 245760    (80kt x 3jt A-frags of gate_w^T, zero j>=40)
//  s1     @ 290816   : 20480     s for f<64, [t][n][d] f32
//  sNT    @ 311296   : 20480+128 s for f>=64, [t][d][n] f32 (+pad for n-overrun reads)
//  bias2T @ 331904   : 20480     gnn_b + all-BN-offset fold, [t][d][n] f32
//  xk     @ 352384   : 41943040+128   x^T bf16 [(b*64+d)][m], 80 B rows
//  xb16   @ 42295552 : 41943040  x bf16 [b][n][d]

__global__ __launch_bounds__(256) void prep(
    const float* __restrict__ x, const float* __restrict__ masker,
    const float* __restrict__ ln_gamma, const float* __restrict__ ln_beta,
    const float* __restrict__ gnn_w, const float* __restrict__ gnn_b,
    const float* __restrict__ bn_gamma, const float* __restrict__ bn_beta,
    const float* __restrict__ bn_mean, const float* __restrict__ bn_var,
    const float* __restrict__ gate_w,
    unsigned short* __restrict__ A1pk, unsigned short* __restrict__ W2pk,
    unsigned short* __restrict__ Gpk, float* __restrict__ s1,
    float* __restrict__ sNT, float* __restrict__ bias2T,
    unsigned short* __restrict__ xk, unsigned short* __restrict__ xb16)
{
  // shared carve: block 40 uses AtL (12.8K); blocks 2048/2049 use wtile+oL (53.8K)
  __shared__ __align__(16) char smem[53760];
  float* AtL   = (float*)smem;            // [2*40*40]
  float* wtile = (float*)smem;            // [128][65]
  float* oL    = (float*)(smem + 33280);  // [40][128]
  const int tid = threadIdx.x;

  // ---- transpose (blocks 0..2047, 4 b each) ----
  if (blockIdx.x < 2048) {
    const int lane = tid & 63, bq = tid >> 6;
    const int b = blockIdx.x * 4 + bq;
    const float* xb = x + (size_t)b * 2560 + lane;
    unsigned u[20];
    #pragma unroll
    for (int mp = 0; mp < 20; ++mp)
      u[mp] = pk2(xb[(2*mp)*64], xb[(2*mp+1)*64]);
    unsigned short* dst = xk + ((size_t)b * 64 + lane) * 40;
    #pragma unroll
    for (int i = 0; i < 5; ++i)
      *(uint4*)(dst + i*8) = make_uint4(u[4*i], u[4*i+1], u[4*i+2], u[4*i+3]);
    // xb16: straight bf16 copy in [b][n][d] order
    const float4* xs4 = (const float4*)(x + (size_t)blockIdx.x * 10240);
    uint2* xd2 = (uint2*)(xb16 + (size_t)blockIdx.x * 10240);
    #pragma unroll
    for (int it = 0; it < 10; ++it) {
      float4 v = xs4[it*256 + tid];
      xd2[it*256 + tid] = make_uint2(pk2(v.x, v.y), pk2(v.z, v.w));
    }
  }

  if (blockIdx.x < 40) {
    const int gid = blockIdx.x * 256 + tid, gsz = 40 * 256;
    // W2 B-frags
    for (int e = gid; e < 16384; e += gsz) {
      int frag = e >> 9, rem = e & 511, lane = rem >> 3, jj = rem & 7;
      int t = frag >> 4, ks = (frag >> 2) & 3, dt = frag & 3;
      int f = ks*32 + (lane >> 4)*8 + jj, d = dt*16 + (lane & 15);
      W2pk[e] = f2b(gnn_w[t*8192 + f*64 + d]);
    }
    // G A-frags of gate_w^T
    for (int e = gid; e < 122880; e += gsz) {
      int frag = e >> 9, rem = e & 511, lane = rem >> 3, jj = rem & 7;
      int kt = frag / 3, jt = frag % 3;
      int fl = kt*32 + (lane >> 4)*8 + jj, j = jt*16 + (lane & 15);
      Gpk[e] = f2b(j < NB ? gate_w[fl*NB + j] : 0.f);
    }
    // s1 [t][n][d]
    for (int e = gid; e < 5120; e += gsz) {
      int t = e / 2560, n = (e % 2560) / 64, d = e & 63;
      int F = (t*NB + n)*128 + d;
      s1[e] = bn_gamma[F] * rsqrtf(bn_var[F] + 1e-5f);
    }
    // sNT [t][d][n]
    for (int e = gid; e < 5120; e += gsz) {
      int t = e / 2560, d = (e % 2560) / 40, n = e % 40;
      int F = (t*NB + n)*128 + 64 + d;
      sNT[e] = bn_gamma[F] * rsqrtf(bn_var[F] + 1e-5f);
    }
  } else if (blockIdx.x == 40) {
    // adjacency -> LN -> mask -> softmax -> A1pk
    for (int col = tid; col < 2 * NB; col += 256) {
      int t = col / NB, n = col % NB;
      float adj[NB];
      for (int m = 0; m < NB; ++m) {
        float p = masker[((t*3+0)*NB+m)*NB+n]
                * masker[((t*3+1)*NB+m)*NB+n]
                * masker[((t*3+2)*NB+m)*NB+n];
        adj[m] = p > 0.f ? p : 0.f;
      }
      float mu = 0.f;
      for (int m = 0; m < NB; ++m) mu += adj[m];
      mu *= (1.f/NB);
      float var = 0.f;
      for (int m = 0; m < NB; ++m) { float dv = adj[m]-mu; var += dv*dv; }
      var *= (1.f/NB);
      float inv = rsqrtf(var + 1e-5f);
      float xm[NB]; float mx = -3e38f;
      for (int m = 0; m < NB; ++m) {
        float lnv = (adj[m]-mu)*inv*ln_gamma[m] + ln_beta[m];
        float v = lnv + (adj[m] != 0.f ? 0.f : -1e9f) + (m==n ? 1.f : 0.f);
        xm[m] = v; mx = fmaxf(mx, v);
      }
      float ssum = 0.f;
      for (int m = 0; m < NB; ++m) { xm[m] = __expf(xm[m]-mx); ssum += xm[m]; }
      float isum = 1.f/ssum;
      for (int m = 0; m < NB; ++m)
        AtL[(t*NB+n)*NB+m] = (adj[m] != 0.f) ? xm[m]*isum : 0.f;
    }
    __syncthreads();
    for (int e = tid; e < 6144; e += 256) {
      int frag = e >> 9, rem = e & 511, lane = rem >> 3, jj = rem & 7;
      int t = frag / 6, r2 = frag % 6, nt = r2 >> 1, ks = r2 & 1;
      int n = nt*16 + (lane & 15);
      int m = ks*32 + (lane >> 4)*8 + jj;
      A1pk[e] = f2b((n < NB && m < NB) ? AtL[(t*NB+n)*NB+m] : 0.f);
    }
  } else if (blockIdx.x >= 2048) {
    // bias2T[t][d][n] = gnn_b[t,n,d] + sum_f o(t,n,f)*W[t,f,d] — LDS-staged mini-GEMM
    const int t = blockIdx.x - 2048;
    for (int e = tid; e < 5120; e += 256) {
      int idx = t*5120 + e;                 // e = n*128+f
      float s = bn_gamma[idx] * rsqrtf(bn_var[idx] + 1e-5f);
      oL[e] = bn_beta[idx] - bn_mean[idx] * s;
    }
    for (int e = tid; e < 8192; e += 256)   // wtile[f][d], pitch 65
      wtile[(e >> 6)*65 + (e & 63)] = gnn_w[t*8192 + e];
    __syncthreads();
    const int d = tid & 63, g = tid >> 6;
    for (int i = 0; i < 10; ++i) {
      const int n = g*10 + i;
      float acc = gnn_b[(t*NB + n)*64 + d];
      #pragma unroll 8
      for (int f = 0; f < 128; ++f)
        acc += oL[n*128 + f] * wtile[f*65 + d];
      bias2T[(t*64 + d)*40 + n] = acc;
    }
  }
}

// kernelM: 2 batches/block, 4096 blocks, 4 blocks/CU. Fused GEMM1+2+3+softmax+pool.
__global__ __launch_bounds__(256, 4) void kernelM(
    const unsigned short* __restrict__ xb16, const unsigned short* __restrict__ xk,
    const unsigned short* __restrict__ A1pk, const unsigned short* __restrict__ W2pk,
    const unsigned short* __restrict__ Gpk, const float* __restrict__ s1,
    const float* __restrict__ sNT, const float* __restrict__ bias2T,
    const float* __restrict__ gate_b, float* __restrict__ out)
{
  __shared__ __align__(16) unsigned short hc[80 * 136];  // 21760 B, rows (b,n)
  __shared__ __align__(16) unsigned short hL[2 * 2568];  // 10272 B
  __shared__ float pj[16 * 48];                          // rows w*4+l (l<2 used)
  __shared__ float wgt[2 * NB];

  const int tid = threadIdx.x;
  const int lane = tid & 63;
  const int w = tid >> 6;
  const int l = lane & 15, q = lane >> 4;
  const int b0 = blockIdx.x * 2;
  unsigned* hcU = (unsigned*)hc;

  // persistent fragments
  v8s b1[2][2];
  #pragma unroll
  for (int i = 0; i < 2; ++i)
    #pragma unroll
    for (int ks = 0; ks < 2; ++ks)
      b1[i][ks] = *(const v8s*)(xk + ((size_t)b0*64 + (w*2+i)*16 + l)*40 + ks*32 + q*8);
  v8s a1[2][3][2];
  #pragma unroll
  for (int t = 0; t < 2; ++t)
    #pragma unroll
    for (int nt = 0; nt < 3; ++nt)
      #pragma unroll
      for (int ks = 0; ks < 2; ++ks)
        a1[t][nt][ks] = *(const v8s*)(A1pk + (((t*3+nt)*2+ks) << 9) + lane*8);
  v8s w2[2][4];
  #pragma unroll
  for (int t = 0; t < 2; ++t)
    #pragma unroll
    for (int ks = 0; ks < 4; ++ks)
      w2[t][ks] = *(const v8s*)(W2pk + (((t*4+ks)*4 + w) << 9) + lane*8);

  uint4 xr[3];   // bf16 x chunks (640 over 768 slots), loaded at t=0, reused t=1

  #pragma unroll
  for (int t = 0; t < 2; ++t) {
    // ---- Phase A: hc x-half = s1 .* x ----
    #pragma unroll
    for (int it = 0; it < 3; ++it) {
      const int c = it*256 + tid;
      if (c < 640) {
        const int row = c >> 3, dp8 = c & 7;        // row=(b,n) 0..79
        if (t == 0)  // u32 units: 1280 per batch
          xr[it] = *(const uint4*)((const unsigned*)xb16 + (size_t)b0*1280 + row*32 + dp8*4);
        const uint4 xv = xr[it];
        const int n = row % NB;
        const float4 sA = *(const float4*)(s1 + (t*NB + n)*64 + dp8*8);
        const float4 sB = *(const float4*)(s1 + (t*NB + n)*64 + dp8*8 + 4);
        uint4 p;
        p.x = pk2(blo(xv.x)*sA.x, bhi(xv.x)*sA.y);
        p.y = pk2(blo(xv.y)*sA.z, bhi(xv.y)*sA.w);
        p.z = pk2(blo(xv.z)*sB.x, bhi(xv.z)*sB.y);
        p.w = pk2(blo(xv.w)*sB.z, bhi(xv.w)*sB.w);
        *(uint4*)(hcU + row*68 + dp8*4) = p;
      }
    }
    // ---- GEMM1 + scale -> hc nei-half ----
    #pragma unroll
    for (int i = 0; i < 2; ++i) {
      const int R = (w*2+i)*16 + l;
      const int bb = R >> 6, d = R & 63;
      #pragma unroll
      for (int nt = 0; nt < 3; ++nt) {
        v4f acc = {0.f, 0.f, 0.f, 0.f};
        acc = __builtin_amdgcn_mfma_f32_16x16x32_bf16(a1[t][nt][0], b1[i][0], acc, 0, 0, 0);
        acc = __builtin_amdgcn_mfma_f32_16x16x32_bf16(a1[t][nt][1], b1[i][1], acc, 0, 0, 0);
        const float4 sv = *(const float4*)(sNT + (t*64+d)*40 + nt*16 + q*4);
        #pragma unroll
        for (int r = 0; r < 4; ++r) {
          int n = nt*16 + q*4 + r;
          if (n < NB) hc[(bb*NB + n)*136 + 64 + d] = f2b(acc[r]*sv[r]);
        }
      }
    }
    __syncthreads();
    // ---- GEMM2 + bias2T -> hL ----
    #pragma unroll
    for (int mt = 0; mt < 5; ++mt) {
      v4f acc = {0.f, 0.f, 0.f, 0.f};
      #pragma unroll
      for (int ks = 0; ks < 4; ++ks) {
        v8s af = *(const v8s*)(hc + (mt*16 + l)*136 + ks*32 + q*8);
        acc = __builtin_amdgcn_mfma_f32_16x16x32_bf16(af, w2[t][ks], acc, 0, 0, 0);
      }
      const int d = w*16 + l;
      const int G = mt*16 + q*4;
      const int bb = (G >= NB) ? 1 : 0, n0 = G - bb*NB;
      const float4 bv = *(const float4*)(bias2T + (t*64+d)*40 + n0);
      #pragma unroll
      for (int r = 0; r < 4; ++r)
        hL[bb*2568 + (n0+r)*64 + d] = f2b(acc[r] + bv[r]);
    }
    __syncthreads();
    // ---- GEMM3: logits (A=Gpk rows j, B=hL cols b; cols use l&1) ----
    v4f ac0 = {0,0,0,0}, ac1 = {0,0,0,0}, ac2 = {0,0,0,0};
    for (int kt = w; kt < 80; kt += 4) {
      v8s bf = *(const v8s*)(hL + (l & 1)*2568 + kt*32 + q*8);
      v8s g0 = *(const v8s*)(Gpk + ((kt*3+0) << 9) + lane*8);
      v8s g1 = *(const v8s*)(Gpk + ((kt*3+1) << 9) + lane*8);
      v8s g2 = *(const v8s*)(Gpk + ((kt*3+2) << 9) + lane*8);
      ac0 = __builtin_amdgcn_mfma_f32_16x16x32_bf16(g0, bf, ac0, 0, 0, 0);
      ac1 = __builtin_amdgcn_mfma_f32_16x16x32_bf16(g1, bf, ac1, 0, 0, 0);
      ac2 = __builtin_amdgcn_mfma_f32_16x16x32_bf16(g2, bf, ac2, 0, 0, 0);
    }
    if (l < 2) {
      #pragma unroll
      for (int r = 0; r < 4; ++r) {
        pj[(w*4 + l)*48 +  0 + q*4 + r] = ac0[r];
        pj[(w*4 + l)*48 + 16 + q*4 + r] = ac1[r];
        pj[(w*4 + l)*48 + 32 + q*4 + r] = ac2[r];
      }
    }
    __syncthreads();
    // ---- softmax over 40 logits per b (8 threads per b) ----
    if (tid < 16) {
      const int bb = tid >> 3, s = tid & 7;
      float lv[5]; float mx = -3e38f;
      #pragma unroll
      for (int i = 0; i < 5; ++i) {
        int j = s*5 + i;
        float v = gate_b[j];
        #pragma unroll
        for (int ww = 0; ww < 4; ++ww) v += pj[(ww*4 + bb)*48 + j];
        lv[i] = v; mx = fmaxf(mx, v);
      }
      #pragma unroll
      for (int m = 1; m < 8; m <<= 1) mx = fmaxf(mx, __shfl_xor(mx, m));
      float es = 0.f;
      #pragma unroll
      for (int i = 0; i < 5; ++i) { lv[i] = __expf(lv[i] - mx); es += lv[i]; }
      #pragma unroll
      for (int m = 1; m < 8; m <<= 1) es += __shfl_xor(es, m);
      float inv = 1.f / es;
      #pragma unroll
      for (int i = 0; i < 5; ++i) wgt[bb*NB + s*5 + i] = lv[i]*inv;
    }
    __syncthreads();
    // ---- pool: waves 0,1 own batches b0+w ----
    if (w < 2) {
      float accp = 0.f;
      #pragma unroll 8
      for (int n = 0; n < NB; ++n)
        accp += b2f16(hL[w*2568 + n*64 + lane]) * wgt[w*NB + n];
      out[((size_t)(b0 + w)*2 + t)*64 + lane] = accp;
    }
  }
}

extern "C" void kernel_launch(void* const* d_in, const int* in_sizes, int n_in,
                              void* d_out, int out_size, void* d_ws, size_t ws_size,
                              hipStream_t stream) {
  const float* x        = (const float*)d_in[0];
  const float* masker   = (const float*)d_in[1];
  const float* ln_gamma = (const float*)d_in[2];
  const float* ln_beta  = (const float*)d_in[3];
  const float* gnn_w    = (const float*)d_in[4];
  const float* gnn_b    = (const float*)d_in[5];
  const float* bn_gamma = (const float*)d_in[6];
  const float* bn_beta  = (const float*)d_in[7];
  const float* bn_mean  = (const float*)d_in[8];
  const float* bn_var   = (const float*)d_in[9];
  const float* gate_w   = (const float*)d_in[10];
  const float* gate_b   = (const float*)d_in[11];
  float* out = (float*)d_out;

  char* ws = (char*)d_ws;
  unsigned short* A1pk   = (unsigned short*)(ws + 0);
  unsigned short* W2pk   = (unsigned short*)(ws + 12288);
  unsigned short* Gpk    = (unsigned short*)(ws + 45056);
  float*          s1     = (float*)(ws + 290816);
  float*          sNT    = (float*)(ws + 311296);
  float*          bias2T = (float*)(ws + 331904);
  unsigned short* xk     = (unsigned short*)(ws + 352384);
  unsigned short* xb16   = (unsigned short*)(ws + 42295552);

  prep<<<2050, 256, 0, stream>>>(x, masker, ln_gamma, ln_beta, gnn_w, gnn_b,
                                 bn_gamma, bn_beta, bn_mean, bn_var, gate_w,
                                 A1pk, W2pk, Gpk, s1, sNT, bias2T, xk, xb16);
  kernelM<<<4096, 256, 0, stream>>>(xb16, xk, A1pk, W2pk, Gpk,
                                    s1, sNT, bias2T, gate_b, out);
}